// Round 10
// baseline (556.570 us; speedup 1.0000x reference)
//
#include <hip/hip_runtime.h>

typedef __attribute__((ext_vector_type(8))) short short8;
typedef __attribute__((ext_vector_type(4))) float f32x4;

#define SS 1024
#define NBLK 64    // lstm blocks (4 batch rows each)
#define HROW 72    // bf16 elems per hbuf row (144 B, 16B-aligned)

__device__ __forceinline__ float sigmoidf_(float x) {
    return __builtin_amdgcn_rcpf(1.0f + __expf(-x));
}
__device__ __forceinline__ float tanhf_(float x) {
    return 1.0f - 2.0f * __builtin_amdgcn_rcpf(__expf(2.0f * x) + 1.0f);
}
__device__ __forceinline__ unsigned short f2bf(float f) {   // RNE f32->bf16
    unsigned int u = __float_as_uint(f);
    u += 0x7fffu + ((u >> 16) & 1u);
    return (unsigned short)(u >> 16);
}
__device__ __forceinline__ float h2f_lo(unsigned int u) {
    _Float16 h; unsigned short s = (unsigned short)(u & 0xffffu);
    __builtin_memcpy(&h, &s, 2); return (float)h;
}
__device__ __forceinline__ float h2f_hi(unsigned int u) {
    _Float16 h; unsigned short s = (unsigned short)(u >> 16);
    __builtin_memcpy(&h, &s, 2); return (float)h;
}
__device__ __forceinline__ unsigned int pkf16(float a, float b) {
    auto p = __builtin_amdgcn_cvt_pkrtz(a, b);   // __fp16 ext_vector(2)
    unsigned int u; __builtin_memcpy(&u, &p, 4); return u;
}

// lgkm-only barrier: global (vmcnt) prefetches/stores stay in flight.
#define RAW_BARRIER() asm volatile("s_waitcnt lgkmcnt(0)\n\ts_barrier" ::: "memory")

#define MF(A, Bv, C) __builtin_amdgcn_mfma_f32_16x16x32_bf16(A, Bv, C, 0, 0, 0)

// ============ Fused producer/consumer LSTM (single kernel) =================
// 64 blocks x 8 waves. Waves 0-3: recurrence consumer at s_setprio(1) --
// priority keeps the serial gate/trans chain from queuing behind producer
// VALU issue (round-8's +200cy/phase regression). Waves 4-7: producers --
// per phase compute xz(p+1) via 8 MFMAs into a 2-slot LDS ring, AND one
// rotating producer wave computes dense out for h(p-2) via the z4 MFMA
// (B-frag col0 = dw) from the idle hbuf parity. No h-stream, no dense_out
// kernel, no xz HBM round-trip.
// Barrier timeline: call k (producer) / phase p=k-1 (consumer) between
// B_{k-1},B_k. h(T) lives in hbuf[T&1]; xz(k) in ring[k&1].

#define LOADB(VAR, G, KC, SRC, NN) do {                                       \
    const int kb = ((KC) << 5) + (q << 3);                                    \
    short8 v;                                                                 \
    v[0] = (short)f2bf(SRC[(kb + 0) * 256 + (NN)]);                           \
    v[1] = (short)f2bf(SRC[(kb + 1) * 256 + (NN)]);                           \
    v[2] = (short)f2bf(SRC[(kb + 2) * 256 + (NN)]);                           \
    v[3] = (short)f2bf(SRC[(kb + 3) * 256 + (NN)]);                           \
    v[4] = (short)f2bf(SRC[(kb + 4) * 256 + (NN)]);                           \
    v[5] = (short)f2bf(SRC[(kb + 5) * 256 + (NN)]);                           \
    v[6] = (short)f2bf(SRC[(kb + 6) * 256 + (NN)]);                           \
    v[7] = (short)f2bf(SRC[(kb + 7) * 256 + (NN)]);                           \
    VAR = v; } while (0)

// -------- consumer phase T (parity PAR = T&1) --------
#define CREGION(T, PAR) do {                                                   \
    const short8 ha0 = *(const short8*)&hbuf[(PAR) ^ 1][m * HROW + (q << 3)];  \
    const short8 ha1 = *(const short8*)&hbuf[(PAR) ^ 1][m * HROW + 32 + (q << 3)]; \
    const uint2 cur = ring[PAR][q][n0];                                        \
    const float vi = h2f_lo(cur.x), vf = h2f_hi(cur.x);                        \
    const float vc = h2f_lo(cur.y), vo = h2f_hi(cur.y);                        \
    const f32x4 cgc = {vc, vc, vc, vc};                                        \
    const f32x4 cgo = {vo, vo, vo, vo};                                        \
    const f32x4 cgi = {vi, vi, vi, vi};                                        \
    const f32x4 cgf = {vf, vf, vf, vf};                                        \
    const f32x4 zc = MF(ha1, BHC1, MF(ha0, BHC0, cgc));                        \
    const f32x4 zo = MF(ha1, BHO1, MF(ha0, BHO0, cgo));                        \
    const f32x4 zi = MF(ha1, BHI1, MF(ha0, BHI0, cgi));                        \
    const f32x4 zf = MF(ha1, BHF1, MF(ha0, BHF0, cgf));                        \
    const float tc = tanhf_(zc[0]);                                            \
    const float go = sigmoidf_(zo[0]);                                         \
    const float gi = sigmoidf_(zi[0]);                                         \
    const float gf = sigmoidf_(zf[0]);                                         \
    cc0 = gf * cc0 + gi * tc;                                                  \
    const float h0 = go * tanhf_(cc0);                                         \
    hbuf[PAR][(q << 2) * HROW + n0] = (short)f2bf(h0);                         \
    RAW_BARRIER();                                                             \
} while (0)

// -------- producer call K: xz(K)->ring[K&1]; dense h(K-2); load x(K+2) -----
#define PCALL(K, RPS, F0, F1, F2, F3) do {                                     \
    if ((K) < SS) {                                                            \
        short8 xa0, xa1;                                                       \
        xa0[0] = (short)f2bf(F0.x); xa0[1] = (short)f2bf(F0.y);                \
        xa0[2] = (short)f2bf(F0.z); xa0[3] = (short)f2bf(F0.w);                \
        xa0[4] = (short)f2bf(F1.x); xa0[5] = (short)f2bf(F1.y);                \
        xa0[6] = (short)f2bf(F1.z); xa0[7] = (short)f2bf(F1.w);                \
        xa1[0] = (short)f2bf(F2.x); xa1[1] = (short)f2bf(F2.y);                \
        xa1[2] = (short)f2bf(F2.z); xa1[3] = (short)f2bf(F2.w);                \
        xa1[4] = (short)f2bf(F3.x); xa1[5] = (short)f2bf(F3.y);                \
        xa1[6] = (short)f2bf(F3.z); xa1[7] = (short)f2bf(F3.w);                \
        const f32x4 zi = MF(xa1, WI1, MF(xa0, WI0, cbi));                      \
        const f32x4 zf = MF(xa1, WF1, MF(xa0, WF0, cbf));                      \
        const f32x4 zc = MF(xa1, WC1, MF(xa0, WC0, cbc));                      \
        const f32x4 zo = MF(xa1, WO1, MF(xa0, WO0, cbo));                      \
        uint2 v;                                                               \
        v.x = pkf16(zi[0], zf[0]);                                             \
        v.y = pkf16(zc[0], zo[0]);                                             \
        ring[RPS][q][pw16m] = v;                                               \
    }                                                                          \
    if ((K) >= 2 && pw == ((K) & 3)) {       /* dense for step K-2 */          \
        const short8 da0 = *(const short8*)&hbuf[(K) & 1][m * HROW + (q << 3)];\
        const short8 da1 = *(const short8*)&hbuf[(K) & 1][m * HROW + 32 + (q << 3)]; \
        const f32x4 zz = {0.f, 0.f, 0.f, 0.f};                                 \
        const f32x4 z4 = MF(da1, BD1, MF(da0, BD0, zz));                       \
        if (m == 0) {                                                          \
            out[((size_t)((bb << 2) + q) << 10) + (K) - 2] =                   \
                sigmoidf_(z4[0] + db0);                                        \
        }                                                                      \
    }                                                                          \
    { const int sn = ((K) + 2 < SS) ? (K) + 2 : SS - 1;                        \
      const float* __restrict__ xs = xp + ((size_t)sn << 6);                   \
      F0 = *(const float4*)(xs + (q << 3));                                    \
      F1 = *(const float4*)(xs + (q << 3) + 4);                                \
      F2 = *(const float4*)(xs + 32 + (q << 3));                               \
      F3 = *(const float4*)(xs + 36 + (q << 3)); }                             \
    RAW_BARRIER();                                                             \
} while (0)

__global__ __launch_bounds__(512, 1)
void lstm_fused(const float* __restrict__ x, const float* __restrict__ wk,
                const float* __restrict__ rk, const float* __restrict__ bias,
                const float* __restrict__ dw, const float* __restrict__ db,
                float* __restrict__ out) {
    const int bb  = blockIdx.x;               // 0..63, 4 batch rows each
    const int tid = threadIdx.x;
    const int l   = tid & 63;
    const int w   = tid >> 6;                 // 0-3 consumer, 4-7 producer
    const int m   = l & 15;
    const int q   = l >> 4;

    __shared__ short hbuf[2][16 * HROW];      // 4.6 KB, double-buffered h
    __shared__ uint2 ring[2][4][64];          // 4 KB, 2-slot xz ring

    for (int i = tid; i < 2 * 16 * HROW; i += 512) ((short*)hbuf)[i] = 0;
    __syncthreads();

    if (w < 4) {
        // ---------------- consumer: recurrence (priority 1) ----------------
        const int n0 = (w << 4) + m;
        short8 BHI0, BHI1, BHF0, BHF1, BHC0, BHC1, BHO0, BHO1;
        LOADB(BHI0, 0, 0, rk, (0 << 6) + n0); LOADB(BHI1, 0, 1, rk, (0 << 6) + n0);
        LOADB(BHF0, 1, 0, rk, (1 << 6) + n0); LOADB(BHF1, 1, 1, rk, (1 << 6) + n0);
        LOADB(BHC0, 2, 0, rk, (2 << 6) + n0); LOADB(BHC1, 2, 1, rk, (2 << 6) + n0);
        LOADB(BHO0, 3, 0, rk, (3 << 6) + n0); LOADB(BHO1, 3, 1, rk, (3 << 6) + n0);

        float cc0 = 0.f;
        __builtin_amdgcn_s_setprio(1);
        RAW_BARRIER();                        // B_0 (producer made xz(0))
        for (int t = 0; t < SS; t += 2) {
            CREGION(t,     0);
            CREGION(t + 1, 1);
        }
    } else {
        // ---------------- producer: xz GEMM + dense output ----------------
        const int pw    = w - 4;              // 0..3
        const int pw16m = (pw << 4) + m;
        short8 WI0, WI1, WF0, WF1, WC0, WC1, WO0, WO1;
        LOADB(WI0, 0, 0, wk, (0 << 6) + pw16m); LOADB(WI1, 0, 1, wk, (0 << 6) + pw16m);
        LOADB(WF0, 1, 0, wk, (1 << 6) + pw16m); LOADB(WF1, 1, 1, wk, (1 << 6) + pw16m);
        LOADB(WC0, 2, 0, wk, (2 << 6) + pw16m); LOADB(WC1, 2, 1, wk, (2 << 6) + pw16m);
        LOADB(WO0, 3, 0, wk, (3 << 6) + pw16m); LOADB(WO1, 3, 1, wk, (3 << 6) + pw16m);

        const float bi = bias[(0 << 6) + pw16m];
        const float bf = bias[(1 << 6) + pw16m];
        const float bc = bias[(2 << 6) + pw16m];
        const float bo = bias[(3 << 6) + pw16m];
        const f32x4 cbi = {bi, bi, bi, bi};
        const f32x4 cbf = {bf, bf, bf, bf};
        const f32x4 cbc = {bc, bc, bc, bc};
        const f32x4 cbo = {bo, bo, bo, bo};

        short8 BD0, BD1;                      // dense B-fragment: col 0 = dw
        {
            short8 v0 = {0, 0, 0, 0, 0, 0, 0, 0}, v1 = v0;
            if (m == 0) {
#pragma unroll
                for (int i = 0; i < 8; ++i) v0[i] = (short)f2bf(dw[(q << 3) + i]);
#pragma unroll
                for (int i = 0; i < 8; ++i) v1[i] = (short)f2bf(dw[32 + (q << 3) + i]);
            }
            BD0 = v0; BD1 = v1;
        }
        const float db0 = db[0];

        // A-row m <- batch (m>>2) of this block (x4 duplicated rows)
        const float* __restrict__ xp =
            x + ((size_t)((bb << 2) + (m >> 2)) << 16);   // *1024*64

        float4 XA0 = *(const float4*)(xp + (q << 3));
        float4 XA1 = *(const float4*)(xp + (q << 3) + 4);
        float4 XA2 = *(const float4*)(xp + 32 + (q << 3));
        float4 XA3 = *(const float4*)(xp + 36 + (q << 3));
        float4 XB0 = *(const float4*)(xp + 64 + (q << 3));
        float4 XB1 = *(const float4*)(xp + 64 + (q << 3) + 4);
        float4 XB2 = *(const float4*)(xp + 96 + (q << 3));
        float4 XB3 = *(const float4*)(xp + 100 + (q << 3));

        PCALL(0, 0, XA0, XA1, XA2, XA3);      // B_0: xz(0) -> ring[0]
        for (int k = 1; k < SS; k += 2) {
            PCALL(k,     1, XB0, XB1, XB2, XB3);
            PCALL(k + 1, 0, XA0, XA1, XA2, XA3);
        }
        // Epilogue (after B_1024): dense for h(SS-1) in hbuf[1].
        if (pw == 1) {
            const short8 da0 = *(const short8*)&hbuf[1][m * HROW + (q << 3)];
            const short8 da1 = *(const short8*)&hbuf[1][m * HROW + 32 + (q << 3)];
            const f32x4 zz = {0.f, 0.f, 0.f, 0.f};
            const f32x4 z4 = MF(da1, BD1, MF(da0, BD0, zz));
            if (m == 0) {
                out[((size_t)((bb << 2) + q) << 10) + SS - 1] =
                    sigmoidf_(z4[0] + db0);
            }
        }
    }
}

// ============ Host ============
extern "C" void kernel_launch(void* const* d_in, const int* in_sizes, int n_in,
                              void* d_out, int out_size, void* d_ws, size_t ws_size,
                              hipStream_t stream) {
    const float* x    = (const float*)d_in[0];
    const float* wk   = (const float*)d_in[1];
    const float* rk   = (const float*)d_in[2];
    const float* bias = (const float*)d_in[3];
    const float* dw   = (const float*)d_in[4];
    const float* db   = (const float*)d_in[5];
    float* out = (float*)d_out;

    hipLaunchKernelGGL(lstm_fused, dim3(NBLK), dim3(512), 0, stream,
                       x, wk, rk, bias, dw, db, out);
}

// Round 11
// 413.152 us; speedup vs baseline: 1.3471x; 1.3471x over previous
//
#include <hip/hip_runtime.h>

typedef __attribute__((ext_vector_type(8))) short short8;
typedef __attribute__((ext_vector_type(4))) float f32x4;

#define SS 1024
#define NBLK 64    // lstm blocks (4 batch rows each)
#define HROW 72    // bf16 elems per hbuf row (144 B, 16B-aligned)

__device__ __forceinline__ float sigmoidf_(float x) {
    return __builtin_amdgcn_rcpf(1.0f + __expf(-x));
}
__device__ __forceinline__ float tanhf_(float x) {
    return 1.0f - 2.0f * __builtin_amdgcn_rcpf(__expf(2.0f * x) + 1.0f);
}
__device__ __forceinline__ unsigned short f2bf(float f) {   // RNE f32->bf16
    unsigned int u = __float_as_uint(f);
    u += 0x7fffu + ((u >> 16) & 1u);
    return (unsigned short)(u >> 16);
}
__device__ __forceinline__ float bf2f(unsigned short u) {
    return __uint_as_float((unsigned int)u << 16);
}
__device__ __forceinline__ float h2f_lo(unsigned int u) {
    _Float16 h; unsigned short s = (unsigned short)(u & 0xffffu);
    __builtin_memcpy(&h, &s, 2); return (float)h;
}
__device__ __forceinline__ float h2f_hi(unsigned int u) {
    _Float16 h; unsigned short s = (unsigned short)(u >> 16);
    __builtin_memcpy(&h, &s, 2); return (float)h;
}
__device__ __forceinline__ unsigned int pkf16(float a, float b) {
    auto p = __builtin_amdgcn_cvt_pkrtz(a, b);   // __fp16 ext_vector(2)
    unsigned int u; __builtin_memcpy(&u, &p, 4); return u;
}
// packed f32x2 -> bf16x2, single VOP3 (no builtin on gfx950; T12 idiom)
__device__ __forceinline__ unsigned int pkbf(float a, float b) {
    unsigned int r;
    asm("v_cvt_pk_bf16_f32 %0, %1, %2" : "=v"(r) : "v"(a), "v"(b));
    return r;
}

// lgkm-only barrier: global (vmcnt) prefetches/stores stay in flight.
#define RAW_BARRIER() asm volatile("s_waitcnt lgkmcnt(0)\n\ts_barrier" ::: "memory")

#define MF(A, Bv, C) __builtin_amdgcn_mfma_f32_16x16x32_bf16(A, Bv, C, 0, 0, 0)

// ============ Kernel 1: fused producer/consumer LSTM =======================
// 64 blocks x 8 waves, round-8 structure (verified 375us) with the producer's
// 16 scalar f2bf (~80 VALU ops/phase) replaced by 8 v_cvt_pk_bf16_f32 --
// producer issue was contending with the consumer's serial chain (879cy
// phase vs 672 solo). No setprio (R9: starved producers behind the shared
// barrier); no dense-in-producer (R9: made a straggler). h streams to hg.

#define LOADB(VAR, G, KC, SRC, NN) do {                                       \
    const int kb = ((KC) << 5) + (q << 3);                                    \
    short8 v;                                                                 \
    v[0] = (short)f2bf(SRC[(kb + 0) * 256 + (NN)]);                           \
    v[1] = (short)f2bf(SRC[(kb + 1) * 256 + (NN)]);                           \
    v[2] = (short)f2bf(SRC[(kb + 2) * 256 + (NN)]);                           \
    v[3] = (short)f2bf(SRC[(kb + 3) * 256 + (NN)]);                           \
    v[4] = (short)f2bf(SRC[(kb + 4) * 256 + (NN)]);                           \
    v[5] = (short)f2bf(SRC[(kb + 5) * 256 + (NN)]);                           \
    v[6] = (short)f2bf(SRC[(kb + 6) * 256 + (NN)]);                           \
    v[7] = (short)f2bf(SRC[(kb + 7) * 256 + (NN)]);                           \
    VAR = v; } while (0)

// -------- consumer phase: one timestep --------
#define CREGION(T, PAR) do {                                                   \
    const short8 ha0 = *(const short8*)&hbuf[(PAR) ^ 1][m * HROW + (q << 3)];  \
    const short8 ha1 = *(const short8*)&hbuf[(PAR) ^ 1][m * HROW + 32 + (q << 3)]; \
    const uint2 cur = ring[PAR][q][n0];                                        \
    const float vi = h2f_lo(cur.x), vf = h2f_hi(cur.x);                        \
    const float vc = h2f_lo(cur.y), vo = h2f_hi(cur.y);                        \
    const f32x4 cgc = {vc, vc, vc, vc};                                        \
    const f32x4 cgo = {vo, vo, vo, vo};                                        \
    const f32x4 cgi = {vi, vi, vi, vi};                                        \
    const f32x4 cgf = {vf, vf, vf, vf};                                        \
    const f32x4 zc = MF(ha1, BHC1, MF(ha0, BHC0, cgc));                        \
    const f32x4 zo = MF(ha1, BHO1, MF(ha0, BHO0, cgo));                        \
    const f32x4 zi = MF(ha1, BHI1, MF(ha0, BHI0, cgi));                        \
    const f32x4 zf = MF(ha1, BHF1, MF(ha0, BHF0, cgf));                        \
    const float tc = tanhf_(zc[0]);                                            \
    const float go = sigmoidf_(zo[0]);                                         \
    const float gi = sigmoidf_(zi[0]);                                         \
    const float gf = sigmoidf_(zf[0]);                                         \
    cc0 = gf * cc0 + gi * tc;                                                  \
    const float h0 = go * tanhf_(cc0);                                         \
    const unsigned short hb16 = f2bf(h0);                                      \
    hbuf[PAR][(q << 2) * HROW + n0] = (short)hb16;                             \
    hb[(size_t)(T) << 6] = hb16;                                               \
    RAW_BARRIER();                                                             \
} while (0)

// -------- producer call S: xz(S) -> ring[S&1]; refill x(S+2) --------
#define PPROD(S, RPS, F0, F1, F2, F3) do {                                     \
    if ((S) < SS) {                                                            \
        unsigned int xu[8];                                                    \
        xu[0] = pkbf(F0.x, F0.y); xu[1] = pkbf(F0.z, F0.w);                    \
        xu[2] = pkbf(F1.x, F1.y); xu[3] = pkbf(F1.z, F1.w);                    \
        xu[4] = pkbf(F2.x, F2.y); xu[5] = pkbf(F2.z, F2.w);                    \
        xu[6] = pkbf(F3.x, F3.y); xu[7] = pkbf(F3.z, F3.w);                    \
        short8 xa0, xa1;                                                       \
        __builtin_memcpy(&xa0, &xu[0], 16);                                    \
        __builtin_memcpy(&xa1, &xu[4], 16);                                    \
        const f32x4 zi = MF(xa1, WI1, MF(xa0, WI0, cbi));                      \
        const f32x4 zf = MF(xa1, WF1, MF(xa0, WF0, cbf));                      \
        const f32x4 zc = MF(xa1, WC1, MF(xa0, WC0, cbc));                      \
        const f32x4 zo = MF(xa1, WO1, MF(xa0, WO0, cbo));                      \
        uint2 v;                                                               \
        v.x = pkf16(zi[0], zf[0]);                                             \
        v.y = pkf16(zc[0], zo[0]);                                             \
        ring[RPS][q][pw16m] = v;                                               \
    }                                                                          \
    { const int sn = ((S) + 2 < SS) ? (S) + 2 : SS - 1;                        \
      const float* __restrict__ xs = xp + ((size_t)sn << 6);                   \
      F0 = *(const float4*)(xs + (q << 3));                                    \
      F1 = *(const float4*)(xs + (q << 3) + 4);                                \
      F2 = *(const float4*)(xs + 32 + (q << 3));                               \
      F3 = *(const float4*)(xs + 36 + (q << 3)); }                             \
    RAW_BARRIER();                                                             \
} while (0)

__global__ __launch_bounds__(512, 1)
void lstm_fused(const float* __restrict__ x, const float* __restrict__ wk,
                const float* __restrict__ rk, const float* __restrict__ bias,
                unsigned short* __restrict__ hg) {
    const int bb  = blockIdx.x;               // 0..63, 4 batch rows each
    const int tid = threadIdx.x;
    const int l   = tid & 63;
    const int w   = tid >> 6;                 // 0-3 consumer, 4-7 producer
    const int m   = l & 15;
    const int q   = l >> 4;

    __shared__ short hbuf[2][16 * HROW];      // 4.6 KB, double-buffered h
    __shared__ uint2 ring[2][4][64];          // 4 KB, 2-slot xz ring

    for (int i = tid; i < 2 * 16 * HROW; i += 512) ((short*)hbuf)[i] = 0;
    __syncthreads();

    if (w < 4) {
        // ---------------- consumer: recurrence ----------------
        const int n0 = (w << 4) + m;
        short8 BHI0, BHI1, BHF0, BHF1, BHC0, BHC1, BHO0, BHO1;
        LOADB(BHI0, 0, 0, rk, (0 << 6) + n0); LOADB(BHI1, 0, 1, rk, (0 << 6) + n0);
        LOADB(BHF0, 1, 0, rk, (1 << 6) + n0); LOADB(BHF1, 1, 1, rk, (1 << 6) + n0);
        LOADB(BHC0, 2, 0, rk, (2 << 6) + n0); LOADB(BHC1, 2, 1, rk, (2 << 6) + n0);
        LOADB(BHO0, 3, 0, rk, (3 << 6) + n0); LOADB(BHO1, 3, 1, rk, (3 << 6) + n0);

        unsigned short* __restrict__ hb =
            hg + ((size_t)((bb << 2) + q) << 16) + n0;
        float cc0 = 0.f;

        RAW_BARRIER();                        // warm-up (producer makes t=0)
        for (int t = 0; t < SS; t += 2) {
            CREGION(t,     0);
            CREGION(t + 1, 1);
        }
    } else {
        // ---------------- producer: xz GEMM ----------------
        const int pw16m = ((w - 4) << 4) + m;
        short8 WI0, WI1, WF0, WF1, WC0, WC1, WO0, WO1;
        LOADB(WI0, 0, 0, wk, (0 << 6) + pw16m); LOADB(WI1, 0, 1, wk, (0 << 6) + pw16m);
        LOADB(WF0, 1, 0, wk, (1 << 6) + pw16m); LOADB(WF1, 1, 1, wk, (1 << 6) + pw16m);
        LOADB(WC0, 2, 0, wk, (2 << 6) + pw16m); LOADB(WC1, 2, 1, wk, (2 << 6) + pw16m);
        LOADB(WO0, 3, 0, wk, (3 << 6) + pw16m); LOADB(WO1, 3, 1, wk, (3 << 6) + pw16m);

        const float bi = bias[(0 << 6) + pw16m];
        const float bf = bias[(1 << 6) + pw16m];
        const float bc = bias[(2 << 6) + pw16m];
        const float bo = bias[(3 << 6) + pw16m];
        const f32x4 cbi = {bi, bi, bi, bi};
        const f32x4 cbf = {bf, bf, bf, bf};
        const f32x4 cbc = {bc, bc, bc, bc};
        const f32x4 cbo = {bo, bo, bo, bo};

        // A-row m <- batch (m>>2) of this block (x4 duplicated rows)
        const float* __restrict__ xp =
            x + ((size_t)((bb << 2) + (m >> 2)) << 16);   // *1024*64

        float4 XA0 = *(const float4*)(xp + (q << 3));
        float4 XA1 = *(const float4*)(xp + (q << 3) + 4);
        float4 XA2 = *(const float4*)(xp + 32 + (q << 3));
        float4 XA3 = *(const float4*)(xp + 36 + (q << 3));
        float4 XB0 = *(const float4*)(xp + 64 + (q << 3));
        float4 XB1 = *(const float4*)(xp + 64 + (q << 3) + 4);
        float4 XB2 = *(const float4*)(xp + 96 + (q << 3));
        float4 XB3 = *(const float4*)(xp + 100 + (q << 3));

        PPROD(0, 0, XA0, XA1, XA2, XA3);      // warm-up: xz(0) -> ring[0]
        for (int t = 0; t < SS; t += 2) {
            PPROD(t + 1, 1, XB0, XB1, XB2, XB3);
            PPROD(t + 2, 0, XA0, XA1, XA2, XA3);
        }
    }
}

// ============ Kernel 2: out = sigmoid(h @ dw + db), coalesced ==============
// 8 threads per row; each lane loads 16 contiguous bytes, 3-step shfl reduce.
__global__ __launch_bounds__(256)
void dense_out(const unsigned short* __restrict__ hg,
               const float* __restrict__ dw, const float* __restrict__ db,
               float* __restrict__ out) {
    const int t   = blockIdx.x * 256 + threadIdx.x;
    const int row = t >> 3;                   // b*1024 + tstep
    const int seg = t & 7;
    const short8 v = ((const short8*)(hg + (size_t)row * 64))[seg];
    const float4 w0 = *(const float4*)(dw + seg * 8);
    const float4 w1 = *(const float4*)(dw + seg * 8 + 4);
    float acc = bf2f((unsigned short)v[0]) * w0.x
              + bf2f((unsigned short)v[1]) * w0.y
              + bf2f((unsigned short)v[2]) * w0.z
              + bf2f((unsigned short)v[3]) * w0.w
              + bf2f((unsigned short)v[4]) * w1.x
              + bf2f((unsigned short)v[5]) * w1.y
              + bf2f((unsigned short)v[6]) * w1.z
              + bf2f((unsigned short)v[7]) * w1.w;
    acc += __shfl_xor(acc, 1, 64);
    acc += __shfl_xor(acc, 2, 64);
    acc += __shfl_xor(acc, 4, 64);
    if (seg == 0) out[row] = sigmoidf_(acc + db[0]);
}

// ============ Host ============
extern "C" void kernel_launch(void* const* d_in, const int* in_sizes, int n_in,
                              void* d_out, int out_size, void* d_ws, size_t ws_size,
                              hipStream_t stream) {
    const float* x    = (const float*)d_in[0];
    const float* wk   = (const float*)d_in[1];
    const float* rk   = (const float*)d_in[2];
    const float* bias = (const float*)d_in[3];
    const float* dw   = (const float*)d_in[4];
    const float* db   = (const float*)d_in[5];
    float* out = (float*)d_out;

    unsigned short* hg = (unsigned short*)d_ws;        // 32 MB h stream

    hipLaunchKernelGGL(lstm_fused, dim3(NBLK), dim3(512), 0, stream,
                       x, wk, rk, bias, hg);
    hipLaunchKernelGGL(dense_out, dim3(8192), dim3(256), 0, stream,
                       hg, dw, db, out);
}

// Round 13
// 409.504 us; speedup vs baseline: 1.3591x; 1.0089x over previous
//
#include <hip/hip_runtime.h>

typedef __attribute__((ext_vector_type(8))) short short8;
typedef __attribute__((ext_vector_type(4))) float f32x4;

#define SS 1024
#define NBLK 64    // lstm blocks (4 batch rows each)
#define HROW 72    // bf16 elems per hbuf row (144 B, 16B-aligned)
#define LOG2E     1.44269504f
#define TWO_LOG2E 2.88539009f

#if __has_builtin(__builtin_amdgcn_exp2f)
#define E2(x) __builtin_amdgcn_exp2f(x)
#else
#define E2(x) exp2f(x)
#endif

__device__ __forceinline__ float sigmoidf_(float x) {      // natural units
    return __builtin_amdgcn_rcpf(1.0f + __expf(-x));
}
// prescaled gates: input already multiplied by log2e (sigm) / 2log2e (tanh).
// Compiler folds the negation into v_exp_f32's source modifier (free).
__device__ __forceinline__ float sigm_p(float x) {
    return __builtin_amdgcn_rcpf(1.0f + E2(-x));
}
__device__ __forceinline__ float tanh_p(float x) {
    return 1.0f - 2.0f * __builtin_amdgcn_rcpf(E2(x) + 1.0f);
}
__device__ __forceinline__ unsigned short f2bf(float f) {  // RNE f32->bf16
    unsigned int u = __float_as_uint(f);
    u += 0x7fffu + ((u >> 16) & 1u);
    return (unsigned short)(u >> 16);
}
__device__ __forceinline__ float bf2f(unsigned short u) {
    return __uint_as_float((unsigned int)u << 16);
}
__device__ __forceinline__ float h2f_lo(unsigned int u) {
    _Float16 h; unsigned short s = (unsigned short)(u & 0xffffu);
    __builtin_memcpy(&h, &s, 2); return (float)h;
}
__device__ __forceinline__ float h2f_hi(unsigned int u) {
    _Float16 h; unsigned short s = (unsigned short)(u >> 16);
    __builtin_memcpy(&h, &s, 2); return (float)h;
}
__device__ __forceinline__ unsigned int pkf16(float a, float b) {
    auto p = __builtin_amdgcn_cvt_pkrtz(a, b);   // __fp16 ext_vector(2)
    unsigned int u; __builtin_memcpy(&u, &p, 4); return u;
}
__device__ __forceinline__ unsigned int pkbf(float a, float b) {
    unsigned int r;
    asm("v_cvt_pk_bf16_f32 %0, %1, %2" : "=v"(r) : "v"(a), "v"(b));
    return r;
}

// lgkm-only barrier: global (vmcnt) prefetches/stores stay in flight.
#define RAW_BARRIER() asm volatile("s_waitcnt lgkmcnt(0)\n\ts_barrier" ::: "memory")

#define MF(A, Bv, C) __builtin_amdgcn_mfma_f32_16x16x32_bf16(A, Bv, C, 0, 0, 0)

// ============ Kernel 1: fused producer/consumer LSTM =======================
// Round-10 verified structure (331us): 2-slot ring, in-phase ring read.
// New vs that baseline (bisection round; round-11's 4-slot prefetch + raw
// exp asm gave NaN): (b) weights/bias prescaled by log2e (i,f,o) / 2log2e
// (c-gate) so gates use v_exp_f32 directly via builtin; (c) persistent MFMA
// C quads (only elem 0 updated/phase -- pad-row elems stay 0).

#define LOADB(VAR, G, KC, SRC, NN, SC) do {                                   \
    const int kb = ((KC) << 5) + (q << 3);                                    \
    short8 v;                                                                 \
    v[0] = (short)f2bf((SC) * SRC[(kb + 0) * 256 + (NN)]);                    \
    v[1] = (short)f2bf((SC) * SRC[(kb + 1) * 256 + (NN)]);                    \
    v[2] = (short)f2bf((SC) * SRC[(kb + 2) * 256 + (NN)]);                    \
    v[3] = (short)f2bf((SC) * SRC[(kb + 3) * 256 + (NN)]);                    \
    v[4] = (short)f2bf((SC) * SRC[(kb + 4) * 256 + (NN)]);                    \
    v[5] = (short)f2bf((SC) * SRC[(kb + 5) * 256 + (NN)]);                    \
    v[6] = (short)f2bf((SC) * SRC[(kb + 6) * 256 + (NN)]);                    \
    v[7] = (short)f2bf((SC) * SRC[(kb + 7) * 256 + (NN)]);                    \
    VAR = v; } while (0)

// -------- consumer phase: one timestep (ring read in-phase, 2-slot) --------
#define CREGION(T, PAR) do {                                                   \
    const short8 ha0 = *(const short8*)&hbuf[(PAR) ^ 1][m * HROW + (q << 3)];  \
    const short8 ha1 = *(const short8*)&hbuf[(PAR) ^ 1][m * HROW + 32 + (q << 3)]; \
    const uint2 cur = ring[PAR][q][n0];                                        \
    pci[0] = h2f_lo(cur.x); pcf[0] = h2f_hi(cur.x);                            \
    pcc[0] = h2f_lo(cur.y); pco[0] = h2f_hi(cur.y);                            \
    const f32x4 zc = MF(ha1, BHC1, MF(ha0, BHC0, pcc));                        \
    const f32x4 zo = MF(ha1, BHO1, MF(ha0, BHO0, pco));                        \
    const f32x4 zi = MF(ha1, BHI1, MF(ha0, BHI0, pci));                        \
    const f32x4 zf = MF(ha1, BHF1, MF(ha0, BHF0, pcf));                        \
    const float tc = tanh_p(zc[0]);                                            \
    const float go = sigm_p(zo[0]);                                            \
    const float gi = sigm_p(zi[0]);                                            \
    const float gf = sigm_p(zf[0]);                                            \
    cc0 = gf * cc0 + gi * tc;                                                  \
    const float h0 = go * tanh_p(TWO_LOG2E * cc0);                             \
    const unsigned short hb16 = f2bf(h0);                                      \
    hbuf[PAR][(q << 2) * HROW + n0] = (short)hb16;                             \
    hb[(size_t)(T) << 6] = hb16;                                               \
    RAW_BARRIER();                                                             \
} while (0)

// -------- producer call S: xz(S) -> ring[S&1]; refill x(S+2) --------
#define PPROD(S, RPS, F0, F1, F2, F3) do {                                     \
    if ((S) < SS) {                                                            \
        unsigned int xu[8];                                                    \
        xu[0] = pkbf(F0.x, F0.y); xu[1] = pkbf(F0.z, F0.w);                    \
        xu[2] = pkbf(F1.x, F1.y); xu[3] = pkbf(F1.z, F1.w);                    \
        xu[4] = pkbf(F2.x, F2.y); xu[5] = pkbf(F2.z, F2.w);                    \
        xu[6] = pkbf(F3.x, F3.y); xu[7] = pkbf(F3.z, F3.w);                    \
        short8 xa0, xa1;                                                       \
        __builtin_memcpy(&xa0, &xu[0], 16);                                    \
        __builtin_memcpy(&xa1, &xu[4], 16);                                    \
        const f32x4 zi = MF(xa1, WI1, MF(xa0, WI0, cbi));                      \
        const f32x4 zf = MF(xa1, WF1, MF(xa0, WF0, cbf));                      \
        const f32x4 zc = MF(xa1, WC1, MF(xa0, WC0, cbc));                      \
        const f32x4 zo = MF(xa1, WO1, MF(xa0, WO0, cbo));                      \
        uint2 v;                                                               \
        v.x = pkf16(zi[0], zf[0]);                                             \
        v.y = pkf16(zc[0], zo[0]);                                             \
        ring[RPS][q][pw16m] = v;                                               \
    }                                                                          \
    { const int sn = ((S) + 2 < SS) ? (S) + 2 : SS - 1;                        \
      const float* __restrict__ xs = xp + ((size_t)sn << 6);                   \
      F0 = *(const float4*)(xs + (q << 3));                                    \
      F1 = *(const float4*)(xs + (q << 3) + 4);                                \
      F2 = *(const float4*)(xs + 32 + (q << 3));                               \
      F3 = *(const float4*)(xs + 36 + (q << 3)); }                             \
    RAW_BARRIER();                                                             \
} while (0)

__global__ __launch_bounds__(512, 1)
void lstm_fused(const float* __restrict__ x, const float* __restrict__ wk,
                const float* __restrict__ rk, const float* __restrict__ bias,
                unsigned short* __restrict__ hg) {
    const int bb  = blockIdx.x;               // 0..63, 4 batch rows each
    const int tid = threadIdx.x;
    const int l   = tid & 63;
    const int w   = tid >> 6;                 // 0-3 consumer, 4-7 producer
    const int m   = l & 15;
    const int q   = l >> 4;

    __shared__ short hbuf[2][16 * HROW];      // 4.6 KB, double-buffered h
    __shared__ uint2 ring[2][4][64];          // 4 KB, 2-slot xz ring

    for (int i = tid; i < 2 * 16 * HROW; i += 512) ((short*)hbuf)[i] = 0;
    __syncthreads();

    if (w < 4) {
        // ---------------- consumer: recurrence ----------------
        const int n0 = (w << 4) + m;
        short8 BHI0, BHI1, BHF0, BHF1, BHC0, BHC1, BHO0, BHO1;
        LOADB(BHI0, 0, 0, rk, (0 << 6) + n0, LOG2E);
        LOADB(BHI1, 0, 1, rk, (0 << 6) + n0, LOG2E);
        LOADB(BHF0, 1, 0, rk, (1 << 6) + n0, LOG2E);
        LOADB(BHF1, 1, 1, rk, (1 << 6) + n0, LOG2E);
        LOADB(BHC0, 2, 0, rk, (2 << 6) + n0, TWO_LOG2E);
        LOADB(BHC1, 2, 1, rk, (2 << 6) + n0, TWO_LOG2E);
        LOADB(BHO0, 3, 0, rk, (3 << 6) + n0, LOG2E);
        LOADB(BHO1, 3, 1, rk, (3 << 6) + n0, LOG2E);

        unsigned short* __restrict__ hb =
            hg + ((size_t)((bb << 2) + q) << 16) + n0;
        float cc0 = 0.f;
        f32x4 pci = {0.f, 0.f, 0.f, 0.f}, pcf = pci, pcc = pci, pco = pci;

        RAW_BARRIER();                        // warm-up (producer makes t=0)
        for (int t = 0; t < SS; t += 2) {
            CREGION(t,     0);
            CREGION(t + 1, 1);
        }
    } else {
        // ---------------- producer: xz GEMM ----------------
        const int pw16m = ((w - 4) << 4) + m;
        short8 WI0, WI1, WF0, WF1, WC0, WC1, WO0, WO1;
        LOADB(WI0, 0, 0, wk, (0 << 6) + pw16m, LOG2E);
        LOADB(WI1, 0, 1, wk, (0 << 6) + pw16m, LOG2E);
        LOADB(WF0, 1, 0, wk, (1 << 6) + pw16m, LOG2E);
        LOADB(WF1, 1, 1, wk, (1 << 6) + pw16m, LOG2E);
        LOADB(WC0, 2, 0, wk, (2 << 6) + pw16m, TWO_LOG2E);
        LOADB(WC1, 2, 1, wk, (2 << 6) + pw16m, TWO_LOG2E);
        LOADB(WO0, 3, 0, wk, (3 << 6) + pw16m, LOG2E);
        LOADB(WO1, 3, 1, wk, (3 << 6) + pw16m, LOG2E);

        const float bi = LOG2E     * bias[(0 << 6) + pw16m];
        const float bf = LOG2E     * bias[(1 << 6) + pw16m];
        const float bc = TWO_LOG2E * bias[(2 << 6) + pw16m];
        const float bo = LOG2E     * bias[(3 << 6) + pw16m];
        const f32x4 cbi = {bi, bi, bi, bi};
        const f32x4 cbf = {bf, bf, bf, bf};
        const f32x4 cbc = {bc, bc, bc, bc};
        const f32x4 cbo = {bo, bo, bo, bo};

        // A-row m <- batch (m>>2) of this block (x4 duplicated rows)
        const float* __restrict__ xp =
            x + ((size_t)((bb << 2) + (m >> 2)) << 16);   // *1024*64

        float4 XA0 = *(const float4*)(xp + (q << 3));
        float4 XA1 = *(const float4*)(xp + (q << 3) + 4);
        float4 XA2 = *(const float4*)(xp + 32 + (q << 3));
        float4 XA3 = *(const float4*)(xp + 36 + (q << 3));
        float4 XB0 = *(const float4*)(xp + 64 + (q << 3));
        float4 XB1 = *(const float4*)(xp + 64 + (q << 3) + 4);
        float4 XB2 = *(const float4*)(xp + 96 + (q << 3));
        float4 XB3 = *(const float4*)(xp + 100 + (q << 3));

        PPROD(0, 0, XA0, XA1, XA2, XA3);      // warm-up: xz(0) -> ring[0]
        for (int t = 0; t < SS; t += 2) {
            PPROD(t + 1, 1, XB0, XB1, XB2, XB3);
            PPROD(t + 2, 0, XA0, XA1, XA2, XA3);
        }
    }
}

// ============ Kernel 2: out = sigmoid(h @ dw + db), coalesced ==============
__global__ __launch_bounds__(256)
void dense_out(const unsigned short* __restrict__ hg,
               const float* __restrict__ dw, const float* __restrict__ db,
               float* __restrict__ out) {
    const int t   = blockIdx.x * 256 + threadIdx.x;
    const int row = t >> 3;                   // b*1024 + tstep
    const int seg = t & 7;
    const short8 v = ((const short8*)(hg + (size_t)row * 64))[seg];
    const float4 w0 = *(const float4*)(dw + seg * 8);
    const float4 w1 = *(const float4*)(dw + seg * 8 + 4);
    float acc = bf2f((unsigned short)v[0]) * w0.x
              + bf2f((unsigned short)v[1]) * w0.y
              + bf2f((unsigned short)v[2]) * w0.z
              + bf2f((unsigned short)v[3]) * w0.w
              + bf2f((unsigned short)v[4]) * w1.x
              + bf2f((unsigned short)v[5]) * w1.y
              + bf2f((unsigned short)v[6]) * w1.z
              + bf2f((unsigned short)v[7]) * w1.w;
    acc += __shfl_xor(acc, 1, 64);
    acc += __shfl_xor(acc, 2, 64);
    acc += __shfl_xor(acc, 4, 64);
    if (seg == 0) out[row] = sigmoidf_(acc + db[0]);
}

// ============ Host ============
extern "C" void kernel_launch(void* const* d_in, const int* in_sizes, int n_in,
                              void* d_out, int out_size, void* d_ws, size_t ws_size,
                              hipStream_t stream) {
    const float* x    = (const float*)d_in[0];
    const float* wk   = (const float*)d_in[1];
    const float* rk   = (const float*)d_in[2];
    const float* bias = (const float*)d_in[3];
    const float* dw   = (const float*)d_in[4];
    const float* db   = (const float*)d_in[5];
    float* out = (float*)d_out;

    unsigned short* hg = (unsigned short*)d_ws;        // 32 MB h stream

    hipLaunchKernelGGL(lstm_fused, dim3(NBLK), dim3(512), 0, stream,
                       x, wk, rk, bias, hg);
    hipLaunchKernelGGL(dense_out, dim3(8192), dim3(256), 0, stream,
                       hg, dw, db, out);
}